// Round 4
// baseline (175.165 us; speedup 1.0000x reference)
//
#include <hip/hip_runtime.h>
#include <math.h>

// SSIM fused single pass, v4 — wave-autonomous tiles, ORDERED.
// v3 failed because the compiler reordered ds_reads above ds_writes (cross-lane
// LDS dependency is invisible to per-thread alias analysis). v4 restores
// correctness while keeping zero inter-wave barriers:
//   * __threadfence_block() between LDS write and read: IR memory fence ->
//     s_waitcnt lgkmcnt(0), wave-local, compiler cannot cross it.
//   * double-buffered wave-private row (j&1): the WAR hazard W_{j+2} vs R_j
//     is separated by fence F_{j+1}; one fence per iter is sufficient.
//   * register prefetch: row j+1 global loads issue right after the fence,
//     consumed by next iter's ds_write -> one compute span of latency hiding.
// Vertical conv: mod-11 scatter accumulators, compile-time slots, first-tap
// assign. Division via v_rcp_f32 (err ~1e-7 << 2.6e-4 threshold).

#define KW 11
#define RAD 5
#define IMG_W 512
#define IMG_H 512
#define TY 34               // output rows per wave tile; 44 iters = 4*11 phases
#define NJB 4
#define LROW 74             // 64 + 2*RAD staged (a,b) pairs per wave row
#define C1F 0.0001f         // 0.01^2
#define C2F 0.0009f         // 0.03^2

typedef float v2f __attribute__((ext_vector_type(2)));

__global__ __launch_bounds__(256) void ssim_fused_kernel(
    const float* __restrict__ img1,
    const float* __restrict__ img2,
    float* __restrict__ out,
    float inv_n)
{
    __shared__ v2f rows[4][2][LROW];   // [wave][double-buffer][pairs]
    __shared__ float red[4];

    const int tid  = threadIdx.x;
    const int lane = tid & 63;
    const int wvi  = tid >> 6;

    const int x0 = (blockIdx.x * 4 + wvi) * 64;  // wave's first output col
    const int y0 = blockIdx.y * TY;              // wave's first output row

    const size_t pbase = (size_t)blockIdx.z * (size_t)(IMG_W * IMG_H);
    const float* __restrict__ p1 = img1 + pbase;
    const float* __restrict__ p2 = img2 + pbase;

    // Gaussian weights in double (matches float64 np reference), SGPR-pinned.
    float g[KW];
    {
        double t[KW];
        double s = 0.0;
        #pragma unroll
        for (int i = 0; i < KW; ++i) {
            const double c = (double)(i - RAD);
            t[i] = exp(-(c * c) / 4.5);   // 2*sigma^2 = 4.5
            s += t[i];
        }
        #pragma unroll
        for (int i = 0; i < KW; ++i) {
            const float gi = (float)(t[i] / s);
            g[i] = __int_as_float(__builtin_amdgcn_readfirstlane(__float_as_int(gi)));
        }
    }

    // Loop-invariant per-lane column geometry (clamped addr + mask-multiply).
    const int c0   = x0 - RAD + lane;
    const int c0c  = min(max(c0, 0), IMG_W - 1);
    const float m0 = (c0 == c0c) ? 1.f : 0.f;
    const int c1   = c0 + 64;                   // halo pair, lanes 0..9 only
    const int c1c  = min(max(c1, 0), IMG_W - 1);
    const float m1 = (c1 == c1c) ? 1.f : 0.f;

    // Loads row (y0-RAD+j); zeroes when the row is out of range (zero pad).
    auto load_row = [&](int j, v2f& v0, v2f& v1) {
        const int ir = y0 - RAD + j;
        v0 = (v2f){0.f, 0.f};
        v1 = (v2f){0.f, 0.f};
        if ((unsigned)ir < (unsigned)IMG_H) {   // wave-uniform branch
            const float* r1 = p1 + ir * IMG_W;  // uniform base, v-offset col
            const float* r2 = p2 + ir * IMG_W;
            v0.x = r1[c0c] * m0;
            v0.y = r2[c0c] * m0;
            if (lane < 2 * RAD) {
                v1.x = r1[c1c] * m1;
                v1.y = r2[c1c] * m1;
            }
        }
    };

    // Vertical scatter accumulators: slot s holds output row m with m%11==s.
    v2f  accMu[KW], accSq[KW];
    float accXy[KW];
    #pragma unroll
    for (int s = 0; s < KW; ++s) {
        accMu[s] = (v2f){0.f, 0.f};
        accSq[s] = (v2f){0.f, 0.f};
        accXy[s] = 0.f;
    }

    v2f cur0, cur1;
    load_row(0, cur0, cur1);

    float acc = 0.f;

    #pragma clang loop unroll(disable)
    for (int jb = 0; jb < NJB; ++jb) {
        #pragma unroll
        for (int P = 0; P < KW; ++P) {
            const int j   = jb * KW + P;        // 0..43
            const int buf = j & 1;
            v2f* __restrict__ wrow = rows[wvi][buf];

            // ---- stage row j from regs into this wave's LDS buffer ----
            wrow[lane] = cur0;
            if (lane < 2 * RAD) wrow[64 + lane] = cur1;
            __threadfence_block();   // lgkmcnt(0), wave-local: orders W_j < R_j
                                     // and (via F_{j+1}) R_j < W_{j+2}

            // ---- prefetch row j+1 into regs (covered by this iter's math) --
            load_row(j + 1, cur0, cur1);   // last iter: uniform-branch no-op/waste

            // ---- horizontal 11-tap conv at col x0+lane (packed a/b) ----
            v2f hmu = (v2f){0.f, 0.f};
            v2f hsq = (v2f){0.f, 0.f};
            float hxy = 0.f;
            #pragma unroll
            for (int k = 0; k < KW; ++k) {
                const v2f ab = wrow[lane + k];                  // ds_read_b64
                const v2f w  = g[k] * ab;                       // v_pk_mul
                hmu += w;                                       // v_pk_add
                hsq = __builtin_elementwise_fma(w, ab, hsq);    // v_pk_fma
                hxy = fmaf(w.x, ab.y, hxy);
            }

            // ---- vertical scatter; slot s==P gets its FIRST tap: assign ----
            #pragma unroll
            for (int s = 0; s < KW; ++s) {
                const float wt = g[(P - s + KW) % KW];
                const v2f wv2 = (v2f){wt, wt};
                if (s == P) {
                    accMu[s] = wv2 * hmu;
                    accSq[s] = wv2 * hsq;
                    accXy[s] = wt * hxy;
                } else {
                    accMu[s] = __builtin_elementwise_fma(wv2, hmu, accMu[s]);
                    accSq[s] = __builtin_elementwise_fma(wv2, hsq, accSq[s]);
                    accXy[s] = fmaf(wt, hxy, accXy[s]);
                }
            }

            // ---- emit output row oy = y0 + j - 10 from slot (P+1)%11 ----
            const int oy = y0 + j - 2 * RAD;
            if (j >= 2 * RAD && oy < IMG_H) {   // wave-uniform
                const int e = (P + 1) % KW;
                const v2f mu    = accMu[e];
                const v2f musq  = mu * mu;
                const float mu12 = mu.x * mu.y;
                const v2f sig   = accSq[e] - musq;     // (sigma1_sq, sigma2_sq)
                const float s12 = accXy[e] - mu12;     // sigma12
                const float num = fmaf(2.f, mu12, C1F) * fmaf(2.f, s12, C2F);
                const float den = (musq.x + musq.y + C1F) * (sig.x + sig.y + C2F);
                acc = fmaf(num, __builtin_amdgcn_rcpf(den), acc);
            }
        }
    }

    // ---- block reduction, one atomic per block ----
    #pragma unroll
    for (int off = 32; off > 0; off >>= 1)
        acc += __shfl_xor(acc, off, 64);
    if (lane == 0) red[wvi] = acc;
    __syncthreads();
    if (tid == 0) {
        const float s = red[0] + red[1] + red[2] + red[3];
        atomicAdd(out, s * inv_n);
    }
}

extern "C" void kernel_launch(void* const* d_in, const int* in_sizes, int n_in,
                              void* d_out, int out_size, void* d_ws, size_t ws_size,
                              hipStream_t stream) {
    (void)in_sizes; (void)n_in; (void)d_ws; (void)ws_size;
    const float* img1 = (const float*)d_in[0];
    const float* img2 = (const float*)d_in[1];
    float* out = (float*)d_out;

    // d_out is re-poisoned to 0xAA before every launch; zero it (capture-safe).
    hipMemsetAsync(out, 0, (size_t)out_size * sizeof(float), stream);

    const float inv_n = 1.0f / (16.0f * 3.0f * 512.0f * 512.0f);
    // 8 col-tiles (2 blocks x 4 waves) x 16 row-tiles (34 rows, last masked)
    dim3 grid(2, 16, 16 * 3);   // 1536 blocks, 6144 waves
    ssim_fused_kernel<<<grid, dim3(256, 1, 1), 0, stream>>>(img1, img2, out, inv_n);
}

// Round 5
// 152.868 us; speedup vs baseline: 1.1459x; 1.1459x over previous
//
#include <hip/hip_runtime.h>
#include <math.h>

// SSIM fused single pass, v5.
// Changes vs v4 (which was correct at 90 us, VALU ~47%, LDS pipe ~40%):
//  * 4 vertical quantities instead of 5: (mu1, mu2, S=E[x^2]+E[y^2], P=E[xy]).
//    SSIM only needs sigma1^2+sigma2^2 as a sum. Acc = 11 x 2 v2f per column.
//  * 2 columns per thread, wave = 128-col strip: the two H windows share one
//    12-pair staged window, read as 7 aligned ds_read_b128 (56 B/px vs 88).
//  * (s,p)=(a^2+b^2, ab) derived in registers for the 12 window pairs; H-conv
//    is then 2 pk_fma per tap per px. V-scatter: 2 pk_fma per slot per px.
//  * Keeps v4's proven ordering: wave-private LDS rows, double-buffered (j&1),
//    one __threadfence_block (wave-local lgkmcnt drain) per iter, register
//    prefetch of row j+1 issued right after the fence.

#define KW 11
#define RAD 5
#define IMG_W 512
#define IMG_H 512
#define TY 34                // output rows per wave tile; 44 iters = 4*11 phases
#define NJB 4
#define NV4 70               // 140 staged (a,b) pairs = 70 v4f per row buffer
#define C1F 0.0001f          // 0.01^2
#define C2F 0.0009f          // 0.03^2

typedef float v2f __attribute__((ext_vector_type(2)));
typedef float v4f __attribute__((ext_vector_type(4)));

__global__ __launch_bounds__(256) void ssim_fused_kernel(
    const float* __restrict__ img1,
    const float* __restrict__ img2,
    float* __restrict__ out,
    float inv_n)
{
    __shared__ v4f rows[4][2][NV4];   // [wave][double-buffer][v4f = 2 (a,b) pairs]
    __shared__ float red[4];

    const int tid  = threadIdx.x;
    const int lane = tid & 63;
    const int wvi  = tid >> 6;

    const int x0 = wvi * 128;              // wave's 128-col strip
    const int y0 = blockIdx.x * TY;        // wave's first output row

    const size_t pbase = (size_t)blockIdx.y * (size_t)(IMG_W * IMG_H);
    const float* __restrict__ p1 = img1 + pbase;
    const float* __restrict__ p2 = img2 + pbase;

    // Gaussian weights in double (matches float64 np reference), SGPR-pinned.
    float g[KW];
    {
        double t[KW];
        double s = 0.0;
        #pragma unroll
        for (int i = 0; i < KW; ++i) {
            const double c = (double)(i - RAD);
            t[i] = exp(-(c * c) / 4.5);   // 2*sigma^2 = 4.5
            s += t[i];
        }
        #pragma unroll
        for (int i = 0; i < KW; ++i) {
            const float gi = (float)(t[i] / s);
            g[i] = __int_as_float(__builtin_amdgcn_readfirstlane(__float_as_int(gi)));
        }
    }

    // Staged entries cover cols x0-6 .. x0+133 (140 entries, even start for
    // aligned float2 loads). Lane t owns entries {2t, 2t+1}; lanes 0..5 also
    // stage halo entries {128+2l, 129+2l}.
    const int cm  = x0 - 6 + 2 * lane;                 // main col (even)
    const int cmc = min(max(cm, 0), IMG_W - 2);        // clamped, even
    const float mm0 = (cm     >= 0 && cm     < IMG_W) ? 1.f : 0.f;
    const float mm1 = (cm + 1 >= 0 && cm + 1 < IMG_W) ? 1.f : 0.f;
    const int ch  = x0 + 122 + 2 * lane;               // halo col (lanes 0..5)
    const int chc = min(max(ch, 0), IMG_W - 2);
    const float mh0 = (ch     < IMG_W) ? 1.f : 0.f;
    const float mh1 = (ch + 1 < IMG_W) ? 1.f : 0.f;

    // Load row (y0-RAD+j) into interleaved+masked (a0,b0,a1,b1) v4f regs.
    auto load_row = [&](int j, v4f& vm, v4f& vh) {
        const int ir = y0 - RAD + j;
        vm = (v4f){0.f, 0.f, 0.f, 0.f};
        vh = (v4f){0.f, 0.f, 0.f, 0.f};
        if ((unsigned)ir < (unsigned)IMG_H) {   // wave-uniform branch
            const float* r1 = p1 + ir * IMG_W;
            const float* r2 = p2 + ir * IMG_W;
            const v2f a = *reinterpret_cast<const v2f*>(r1 + cmc);
            const v2f b = *reinterpret_cast<const v2f*>(r2 + cmc);
            vm = (v4f){a.x * mm0, b.x * mm0, a.y * mm1, b.y * mm1};
            if (lane < 6) {
                const v2f ah = *reinterpret_cast<const v2f*>(r1 + chc);
                const v2f bh = *reinterpret_cast<const v2f*>(r2 + chc);
                vh = (v4f){ah.x * mh0, bh.x * mh0, ah.y * mh1, bh.y * mh1};
            }
        }
    };

    // V scatter accumulators for the thread's 2 columns (A=2lane, B=2lane+1):
    // slot s holds output row m with m%11==s.  (mu1,mu2) and (S,P) per px.
    v2f aMuA[KW], aSPA[KW], aMuB[KW], aSPB[KW];
    #pragma unroll
    for (int s = 0; s < KW; ++s) {
        aMuA[s] = (v2f){0.f, 0.f}; aSPA[s] = (v2f){0.f, 0.f};
        aMuB[s] = (v2f){0.f, 0.f}; aSPB[s] = (v2f){0.f, 0.f};
    }

    v4f curm, curh;
    load_row(0, curm, curh);

    float acc = 0.f;

    #pragma clang loop unroll(disable)
    for (int jb = 0; jb < NJB; ++jb) {
        #pragma unroll
        for (int P = 0; P < KW; ++P) {
            const int j   = jb * KW + P;        // 0..43
            const int buf = j & 1;
            v4f* __restrict__ wrow = rows[wvi][buf];

            // ---- stage row j (regs -> wave-private LDS) ----
            wrow[lane] = curm;                          // ds_write_b128
            if (lane < 6) wrow[64 + lane] = curh;
            __threadfence_block();   // wave-local lgkmcnt drain; orders W_j < R_j
                                     // and (via F_{j+1}) R_j < W_{j+2}

            // ---- prefetch row j+1 (latency covered by this iter's math) ----
            load_row(j + 1, curm, curh);

            // ---- read the 14-pair window: v4f slots lane..lane+6 ----
            v4f e[7];
            #pragma unroll
            for (int r = 0; r < 7; ++r) e[r] = wrow[lane + r];   // ds_read_b128

            // pairs: idx 0..13; pair(i) = i even ? e[i/2].xy : e[i/2].zw
            // window for col A uses pairs 1..11, col B uses pairs 2..12.
            v2f ab[14], sp[14];
            #pragma unroll
            for (int i = 0; i < 14; ++i) {
                const v4f q = e[i >> 1];
                const v2f t = (i & 1) ? (v2f){q.z, q.w} : (v2f){q.x, q.y};
                ab[i] = t;
            }
            #pragma unroll
            for (int i = 1; i <= 12; ++i) {
                const v2f t = ab[i];
                sp[i] = (v2f){fmaf(t.x, t.x, t.y * t.y), t.x * t.y};
            }

            // ---- horizontal 11-tap conv, 2 px, packed ----
            v2f hMuA = (v2f){0.f, 0.f}, hSPA = (v2f){0.f, 0.f};
            v2f hMuB = (v2f){0.f, 0.f}, hSPB = (v2f){0.f, 0.f};
            #pragma unroll
            for (int k = 0; k < KW; ++k) {
                const v2f gk = (v2f){g[k], g[k]};
                hMuA = __builtin_elementwise_fma(gk, ab[1 + k], hMuA);
                hSPA = __builtin_elementwise_fma(gk, sp[1 + k], hSPA);
                hMuB = __builtin_elementwise_fma(gk, ab[2 + k], hMuB);
                hSPB = __builtin_elementwise_fma(gk, sp[2 + k], hSPB);
            }

            // ---- vertical scatter; slot s==P gets its FIRST tap: assign ----
            #pragma unroll
            for (int s = 0; s < KW; ++s) {
                const float wt = g[(P - s + KW) % KW];
                const v2f wv2 = (v2f){wt, wt};
                if (s == P) {
                    aMuA[s] = wv2 * hMuA;  aSPA[s] = wv2 * hSPA;
                    aMuB[s] = wv2 * hMuB;  aSPB[s] = wv2 * hSPB;
                } else {
                    aMuA[s] = __builtin_elementwise_fma(wv2, hMuA, aMuA[s]);
                    aSPA[s] = __builtin_elementwise_fma(wv2, hSPA, aSPA[s]);
                    aMuB[s] = __builtin_elementwise_fma(wv2, hMuB, aMuB[s]);
                    aSPB[s] = __builtin_elementwise_fma(wv2, hSPB, aSPB[s]);
                }
            }

            // ---- emit output row oy = y0 + j - 10 from slot (P+1)%11 ----
            const int oy = y0 + j - 2 * RAD;
            if (j >= 2 * RAD && oy < IMG_H) {   // wave-uniform
                const int e2 = (P + 1) % KW;
                #pragma unroll
                for (int px = 0; px < 2; ++px) {
                    const v2f mu = px ? aMuB[e2] : aMuA[e2];
                    const v2f SP = px ? aSPB[e2] : aSPA[e2];
                    const v2f musq = mu * mu;
                    const float mu12  = mu.x * mu.y;
                    const float musum = musq.x + musq.y;
                    const float ssum  = SP.x - musum;          // sigma1^2+sigma2^2
                    const float s12   = SP.y - mu12;           // sigma12
                    const float num = fmaf(2.f, mu12, C1F) * fmaf(2.f, s12, C2F);
                    const float den = (musum + C1F) * (ssum + C2F);
                    acc = fmaf(num, __builtin_amdgcn_rcpf(den), acc);
                }
            }
        }
    }

    // ---- block reduction, one atomic per block ----
    #pragma unroll
    for (int off = 32; off > 0; off >>= 1)
        acc += __shfl_xor(acc, off, 64);
    if (lane == 0) red[wvi] = acc;
    __syncthreads();
    if (tid == 0) {
        const float s = red[0] + red[1] + red[2] + red[3];
        atomicAdd(out, s * inv_n);
    }
}

extern "C" void kernel_launch(void* const* d_in, const int* in_sizes, int n_in,
                              void* d_out, int out_size, void* d_ws, size_t ws_size,
                              hipStream_t stream) {
    (void)in_sizes; (void)n_in; (void)d_ws; (void)ws_size;
    const float* img1 = (const float*)d_in[0];
    const float* img2 = (const float*)d_in[1];
    float* out = (float*)d_out;

    // d_out is re-poisoned to 0xAA before every launch; zero it (capture-safe).
    hipMemsetAsync(out, 0, (size_t)out_size * sizeof(float), stream);

    const float inv_n = 1.0f / (16.0f * 3.0f * 512.0f * 512.0f);
    // 16 y-tiles (34 rows, tail masked) x 48 planes; 4 waves = 4 col-strips.
    dim3 grid(16, 48, 1);   // 768 blocks = exactly 3 blocks/CU
    ssim_fused_kernel<<<grid, dim3(256, 1, 1), 0, stream>>>(img1, img2, out, inv_n);
}